// Round 1
// baseline (924.469 us; speedup 1.0000x reference)
//
#include <hip/hip_runtime.h>

// ---------------------------------------------------------------------------
// SharedAtomModel: pooled-embedding encoder -> sparse dictionary top-k -> heads
//
// Sizes: B=1024 S=32 D=512 DICT=16384 TOPK=32
// Outputs (fp32, flat): [1024x16][1024x6][1024x16][1024x6][4 x 1024x16384]
//
// Strategy:
//  - pool + 2-layer MLP in fp64 (tiny; makes our coeffs ~exact vs numpy ref)
//  - combined weights Wq = router + 0.3*delta in fp16; approx coeffs via
//    mfma_f32_16x16x32_f16 (error ~5e-5 abs, candidate margin ~0.02 => safe)
//  - approx fp16 rows staged in d_out sparse region (first half of each row)
//  - per-row: bit-key histogram -> candidate set (>= top-64) -> exact fp64
//    recompute of 64 candidates -> top-32 by (|v| desc, idx asc) -> scatter +
//    rep = sum v*atoms[idx]
//  - heads in fp64
// ws use ~66 MB.
// ---------------------------------------------------------------------------

typedef _Float16 f16x8 __attribute__((ext_vector_type(8)));
typedef _Float16 f16x4 __attribute__((ext_vector_type(4)));
typedef float f32x4 __attribute__((ext_vector_type(4)));

#define OUT_SPARSE 45056
#define SPARSE_PER 16777216

// ---------------- K1: pooled mean embedding (fp64 accumulate) --------------
__global__ __launch_bounds__(128) void pool_kernel(
    const int* __restrict__ ct, const int* __restrict__ nt,
    const float* __restrict__ emb, double* __restrict__ xout)
{
    const int row = blockIdx.x, s = blockIdx.y;
    const int tid = threadIdx.x;
    __shared__ int tk[32];
    const int* t = (s ? nt : ct) + row * 32;
    if (tid < 32) tk[tid] = t[tid];
    __syncthreads();
    const int d = tid * 4;
    double a0 = 0, a1 = 0, a2 = 0, a3 = 0;
    for (int i = 0; i < 32; ++i) {
        const float4 v = *(const float4*)(emb + (size_t)tk[i] * 512 + d);
        a0 += (double)v.x; a1 += (double)v.y; a2 += (double)v.z; a3 += (double)v.w;
    }
    double* o = xout + ((size_t)s * 1024 + row) * 512 + d;
    o[0] = a0 * 0.03125; o[1] = a1 * 0.03125; o[2] = a2 * 0.03125; o[3] = a3 * 0.03125;
}

// ---------------- K2/K3: fp64 encoder GEMM: C = f(A @ W^T + b) -------------
// A: [2048 x 512] fp64, W: [512 x 512] fp32, C: [2048 x 512] fp64
__global__ __launch_bounds__(256) void enc_gemm(
    const double* __restrict__ A, const float* __restrict__ W,
    const float* __restrict__ bias, double* __restrict__ C,
    _Float16* __restrict__ C16, int act)
{
    __shared__ double Ask[16][68];
    __shared__ double Wsk[16][68];
    const int tid = threadIdx.x;
    const int m0 = blockIdx.y * 64, n0 = blockIdx.x * 64;
    const int ty = tid >> 4, tx = tid & 15;
    const int r = tid >> 2, c4 = (tid & 3) * 4;
    double acc[4][4] = {};
    for (int k0 = 0; k0 < 512; k0 += 16) {
        const double4 av = *(const double4*)(A + (size_t)(m0 + r) * 512 + k0 + c4);
        const float4  wv = *(const float4*) (W + (size_t)(n0 + r) * 512 + k0 + c4);
        __syncthreads();
        Ask[c4 + 0][r] = av.x; Ask[c4 + 1][r] = av.y; Ask[c4 + 2][r] = av.z; Ask[c4 + 3][r] = av.w;
        Wsk[c4 + 0][r] = (double)wv.x; Wsk[c4 + 1][r] = (double)wv.y;
        Wsk[c4 + 2][r] = (double)wv.z; Wsk[c4 + 3][r] = (double)wv.w;
        __syncthreads();
#pragma unroll
        for (int k = 0; k < 16; ++k) {
            const double4 a = *(const double4*)&Ask[k][ty * 4];
            const double4 b = *(const double4*)&Wsk[k][tx * 4];
            const double aa[4] = {a.x, a.y, a.z, a.w};
            const double bb[4] = {b.x, b.y, b.z, b.w};
#pragma unroll
            for (int i = 0; i < 4; ++i)
#pragma unroll
                for (int j = 0; j < 4; ++j) acc[i][j] += aa[i] * bb[j];
        }
    }
#pragma unroll
    for (int i = 0; i < 4; ++i) {
        const int row = m0 + ty * 4 + i;
#pragma unroll
        for (int j = 0; j < 4; ++j) {
            const int col = n0 + tx * 4 + j;
            double v = acc[i][j] + (double)bias[col];
            if (act) v = v / (1.0 + exp(-v));   // silu
            C[(size_t)row * 512 + col] = v;
            if (C16) C16[(size_t)row * 512 + col] = (_Float16)v;
        }
    }
}

// ---------------- K4: combined fp16 weights --------------------------------
__global__ __launch_bounds__(256) void combine_kernel(
    const float* __restrict__ router, const float* __restrict__ cd,
    const float* __restrict__ rd, _Float16* __restrict__ wc,
    _Float16* __restrict__ wr)
{
    const size_t i = ((size_t)blockIdx.x * 256 + threadIdx.x) * 4;
    if (i >= (size_t)16384 * 512) return;
    const float4 r = *(const float4*)(router + i);
    const float4 c = *(const float4*)(cd + i);
    const float4 d = *(const float4*)(rd + i);
    f16x4 hc = { (_Float16)(r.x + 0.3f * c.x), (_Float16)(r.y + 0.3f * c.y),
                 (_Float16)(r.z + 0.3f * c.z), (_Float16)(r.w + 0.3f * c.w) };
    f16x4 hr = { (_Float16)(r.x + 0.3f * d.x), (_Float16)(r.y + 0.3f * d.y),
                 (_Float16)(r.z + 0.3f * d.z), (_Float16)(r.w + 0.3f * d.w) };
    *(f16x4*)(wc + i) = hc;
    *(f16x4*)(wr + i) = hr;
}

// ---------------- K5: fp16 MFMA approx coeff GEMM --------------------------
// C[1024 x 16384] (per combo) = P[1024x512] @ W[16384x512]^T, fp16 out staged
// into the first half of each output row of the sparse region.
__global__ __launch_bounds__(256) void approx_gemm(
    const _Float16* __restrict__ P, const _Float16* __restrict__ Wc,
    const _Float16* __restrict__ Wr, float* __restrict__ outf)
{
    __shared__ _Float16 As[128 * 32];
    __shared__ _Float16 Bs[128 * 32];
    __shared__ _Float16 Cst[128 * 128];

    const int tid = threadIdx.x;
    const int q = blockIdx.z;
    const int n0 = blockIdx.x * 128, m0 = blockIdx.y * 128;
    const _Float16* A = P + (size_t)(q >> 1) * 524288;
    const _Float16* B = (q & 1) ? Wr : Wc;

    const int c0 = tid * 2, c1 = tid * 2 + 1;
    const int lane = tid & 63, w = tid >> 6;
    const int wm = w & 1, wn = w >> 1;
    const int lr = lane & 15, lk = lane >> 4;

    const f32x4 zero = {0.f, 0.f, 0.f, 0.f};
    f32x4 acc[4][4];
#pragma unroll
    for (int i = 0; i < 4; ++i)
#pragma unroll
        for (int j = 0; j < 4; ++j) acc[i][j] = zero;

    for (int kt = 0; kt < 16; ++kt) {
        const int k0 = kt * 32;
        const f16x8 a0v = *(const f16x8*)(A + (size_t)(m0 + (c0 >> 2)) * 512 + k0 + (c0 & 3) * 8);
        const f16x8 a1v = *(const f16x8*)(A + (size_t)(m0 + (c1 >> 2)) * 512 + k0 + (c1 & 3) * 8);
        const f16x8 b0v = *(const f16x8*)(B + (size_t)(n0 + (c0 >> 2)) * 512 + k0 + (c0 & 3) * 8);
        const f16x8 b1v = *(const f16x8*)(B + (size_t)(n0 + (c1 >> 2)) * 512 + k0 + (c1 & 3) * 8);
        __syncthreads();
        *(f16x8*)(As + c0 * 8) = a0v;
        *(f16x8*)(As + c1 * 8) = a1v;
        *(f16x8*)(Bs + c0 * 8) = b0v;
        *(f16x8*)(Bs + c1 * 8) = b1v;
        __syncthreads();
        f16x8 af[4], bf[4];
#pragma unroll
        for (int i = 0; i < 4; ++i) af[i] = *(const f16x8*)(As + (wm * 64 + i * 16 + lr) * 32 + lk * 8);
#pragma unroll
        for (int j = 0; j < 4; ++j) bf[j] = *(const f16x8*)(Bs + (wn * 64 + j * 16 + lr) * 32 + lk * 8);
#pragma unroll
        for (int i = 0; i < 4; ++i)
#pragma unroll
            for (int j = 0; j < 4; ++j)
                acc[i][j] = __builtin_amdgcn_mfma_f32_16x16x32_f16(af[i], bf[j], acc[i][j], 0, 0, 0);
    }
    __syncthreads();
    // C/D layout: col = lane&15, row = (lane>>4)*4 + reg  [m89-verified]
#pragma unroll
    for (int i = 0; i < 4; ++i)
#pragma unroll
        for (int j = 0; j < 4; ++j)
#pragma unroll
            for (int rr = 0; rr < 4; ++rr)
                Cst[(wm * 64 + i * 16 + lk * 4 + rr) * 128 + (wn * 64 + j * 16 + lr)] =
                    (_Float16)acc[i][j][rr];
    __syncthreads();
    // coalesced 16B stores; row stride in the sparse region = 32768 ushorts
    unsigned short* ob = (unsigned short*)outf + (size_t)2 * OUT_SPARSE + (size_t)q * 2 * SPARSE_PER;
#pragma unroll
    for (int p = 0; p < 8; ++p) {
        const int cc = p * 256 + tid;
        const int rl = cc >> 4;
        const int ch = (cc & 15) * 8;
        const float4 v = *(const float4*)(Cst + rl * 128 + ch);
        *(float4*)(ob + (size_t)(m0 + rl) * 32768 + n0 + ch) = v;
    }
}

// ---------------- K6: select + exact recompute + scatter + rep -------------
__global__ __launch_bounds__(256) void select_kernel(
    const double* __restrict__ pw, const float* __restrict__ router,
    const float* __restrict__ cdelta, const float* __restrict__ rdelta,
    const float* __restrict__ atoms, float* __restrict__ outf,
    float* __restrict__ repw)
{
    constexpr int NCAP = 320, NRE = 64;
    const int row = blockIdx.x, q = blockIdx.y;
    const int pset = q >> 1;
    const int tid = threadIdx.x;

    __shared__ __align__(16) unsigned short rowv[16384];
    __shared__ unsigned hist[1024];
    __shared__ unsigned pscan[256];
    __shared__ double prow[512];
    __shared__ int cidx[NCAP];
    __shared__ unsigned short ckey[NCAP];
    __shared__ int r64i[NRE];
    __shared__ double cval[NRE];
    __shared__ float selv[32];
    __shared__ int seli[32];
    __shared__ int cnt, bstar;

    float* orow = outf + (size_t)OUT_SPARSE + (size_t)q * SPARSE_PER + (size_t)row * 16384;
    const double* prg = pw + ((size_t)pset * 1024 + row) * 512;

    for (int b = tid; b < 1024; b += 256) hist[b] = 0;
    if (tid == 0) { cnt = 0; bstar = -1; }
    prow[tid] = prg[tid];
    prow[tid + 256] = prg[tid + 256];
    __syncthreads();

    // load approx fp16 row into LDS + histogram of abs-bit keys
    const uint4* arow = (const uint4*)orow;
    uint4* rv4 = (uint4*)rowv;
#pragma unroll
    for (int p = 0; p < 8; ++p) {
        const uint4 v = arow[p * 256 + tid];
        rv4[p * 256 + tid] = v;
        const unsigned uu[4] = {v.x, v.y, v.z, v.w};
#pragma unroll
        for (int e = 0; e < 4; ++e) {
            atomicAdd(&hist[(uu[e] & 0x7FFFu) >> 5], 1u);
            atomicAdd(&hist[((uu[e] >> 16) & 0x7FFFu) >> 5], 1u);
        }
    }
    __syncthreads();

    // zero-fill the dense output row (approx copy already in LDS)
    const float4 z4 = {0.f, 0.f, 0.f, 0.f};
    float4* o4 = (float4*)orow;
#pragma unroll
    for (int p = 0; p < 16; ++p) o4[p * 256 + tid] = z4;

    // suffix-scan histogram from the top to find candidate key threshold
    const unsigned h0 = hist[tid * 4], h1 = hist[tid * 4 + 1];
    const unsigned h2 = hist[tid * 4 + 2], h3 = hist[tid * 4 + 3];
    const unsigned l3 = h3, l2 = h2 + l3, l1 = h1 + l2, l0 = h0 + l1;
    pscan[tid] = l0;
    __syncthreads();
    for (int s = 1; s < 256; s <<= 1) {
        const unsigned v = (tid + s < 256) ? pscan[tid + s] : 0u;
        __syncthreads();
        pscan[tid] += v;
        __syncthreads();
    }
    {
        const unsigned above = (tid < 255) ? pscan[tid + 1] : 0u;
        int best = -1;
        if (l0 + above >= 64u) best = tid * 4;
        if (l1 + above >= 64u) best = tid * 4 + 1;
        if (l2 + above >= 64u) best = tid * 4 + 2;
        if (l3 + above >= 64u) best = tid * 4 + 3;
        if (best >= 0) atomicMax(&bstar, best);
    }
    __syncthreads();
    const unsigned kmin = (unsigned)(bstar < 0 ? 0 : bstar) << 5;

    // collect candidates (all values with key >= kmin; superset of approx top-64)
#pragma unroll
    for (int p = 0; p < 8; ++p) {
        const uint4 v = rv4[p * 256 + tid];
        const unsigned uu[4] = {v.x, v.y, v.z, v.w};
        const int base = (p * 256 + tid) * 8;
#pragma unroll
        for (int e = 0; e < 4; ++e) {
            const unsigned k0 = uu[e] & 0x7FFFu, k1 = (uu[e] >> 16) & 0x7FFFu;
            if (k0 >= kmin) { const int pos = atomicAdd(&cnt, 1); if (pos < NCAP) { cidx[pos] = base + e * 2;     ckey[pos] = (unsigned short)k0; } }
            if (k1 >= kmin) { const int pos = atomicAdd(&cnt, 1); if (pos < NCAP) { cidx[pos] = base + e * 2 + 1; ckey[pos] = (unsigned short)k1; } }
        }
    }
    __syncthreads();
    const int nc = min(cnt, NCAP);

    // approx-rank candidates; keep top NRE (rank unique => race-free)
    for (int p = tid; p < nc; p += 256) {
        const unsigned mk = ckey[p];
        const int mi = cidx[p];
        int rr = 0;
        for (int j = 0; j < nc; ++j) {
            const unsigned kj = ckey[j];
            rr += (kj > mk || (kj == mk && cidx[j] < mi)) ? 1 : 0;
        }
        if (rr < NRE) r64i[rr] = mi;
    }
    __syncthreads();

    // exact fp64 recompute: c = p.router_row + 0.3 * p.delta_row
    const float* drow = (q & 1) ? rdelta : cdelta;
    const int w = tid >> 6, lane = tid & 63;
    for (int c = w; c < NRE; c += 4) {
        const int idx = r64i[c];
        const float4* rp4 = (const float4*)(router + (size_t)idx * 512);
        const float4* dp4 = (const float4*)(drow + (size_t)idx * 512);
        const float4 r0 = rp4[lane * 2], r1 = rp4[lane * 2 + 1];
        const float4 d0 = dp4[lane * 2], d1 = dp4[lane * 2 + 1];
        const double* pv = prow + lane * 8;
        double aR = pv[0] * (double)r0.x + pv[1] * (double)r0.y + pv[2] * (double)r0.z + pv[3] * (double)r0.w
                  + pv[4] * (double)r1.x + pv[5] * (double)r1.y + pv[6] * (double)r1.z + pv[7] * (double)r1.w;
        double aD = pv[0] * (double)d0.x + pv[1] * (double)d0.y + pv[2] * (double)d0.z + pv[3] * (double)d0.w
                  + pv[4] * (double)d1.x + pv[5] * (double)d1.y + pv[6] * (double)d1.z + pv[7] * (double)d1.w;
        for (int sh = 32; sh > 0; sh >>= 1) { aR += __shfl_down(aR, sh); aD += __shfl_down(aD, sh); }
        if (lane == 0) cval[c] = aR + 0.3 * aD;
    }
    __syncthreads();

    // exact top-32 by (|v| desc, idx asc) -- matches lax.top_k tie semantics
    if (tid < NRE) {
        const double av = fabs(cval[tid]);
        const int mi = r64i[tid];
        int rr = 0;
        for (int j = 0; j < NRE; ++j) {
            const double aj = fabs(cval[j]);
            rr += (aj > av || (aj == av && r64i[j] < mi)) ? 1 : 0;
        }
        if (rr < 32) {
            const float fv = (float)cval[tid];
            selv[rr] = fv; seli[rr] = mi;
            orow[mi] = fv;                       // scatter signed value
        }
    }
    __syncthreads();

    // rep = sum_k v_k * atoms[idx_k]
    double a0 = 0, a1 = 0;
    for (int k = 0; k < 32; ++k) {
        const double v = (double)selv[k];
        const float* ar = atoms + (size_t)seli[k] * 512;
        a0 += v * (double)ar[tid];
        a1 += v * (double)ar[tid + 256];
    }
    float* rp = repw + ((size_t)q * 1024 + row) * 512;
    rp[tid] = (float)a0;
    rp[tid + 256] = (float)a1;
}

// ---------------- K7: fused + heads ----------------------------------------
__global__ __launch_bounds__(256) void heads_kernel(
    const double* __restrict__ pw, const float* __restrict__ repw,
    const float* __restrict__ chw, const float* __restrict__ chb,
    const float* __restrict__ rhw, const float* __restrict__ rhb,
    float* __restrict__ out)
{
    const int row = blockIdx.x, s = blockIdx.y;
    const int tid = threadIdx.x;
    __shared__ double fused[512];
    const double* pr = pw + ((size_t)s * 1024 + row) * 512;
    const float* rc = repw + ((size_t)(s * 2 + 0) * 1024 + row) * 512;
    const float* rr = repw + ((size_t)(s * 2 + 1) * 1024 + row) * 512;
    for (int d = tid; d < 512; d += 256)
        fused[d] = 0.2 * pr[d] + 0.9 * (double)rc[d] + 0.9 * (double)rr[d];
    __syncthreads();
    const int w = tid >> 6, lane = tid & 63;
    for (int o = w; o < 22; o += 4) {
        const float* hw = (o < 16) ? (chw + (size_t)o * 512) : (rhw + (size_t)(o - 16) * 512);
        double acc = 0;
#pragma unroll
        for (int j = 0; j < 8; ++j) acc += fused[lane + 64 * j] * (double)hw[lane + 64 * j];
        for (int sh = 32; sh > 0; sh >>= 1) acc += __shfl_down(acc, sh);
        if (lane == 0) {
            if (o < 16) out[(s ? 22528 : 0) + row * 16 + o] = (float)(acc + (double)chb[o]);
            else        out[(s ? 38912 : 16384) + row * 6 + (o - 16)] = (float)(acc + (double)rhb[o - 16]);
        }
    }
}

// ---------------------------------------------------------------------------
extern "C" void kernel_launch(void* const* d_in, const int* in_sizes, int n_in,
                              void* d_out, int out_size, void* d_ws, size_t ws_size,
                              hipStream_t stream)
{
    const int*   ctok   = (const int*)d_in[0];
    const int*   ntok   = (const int*)d_in[1];
    const float* emb    = (const float*)d_in[2];
    const float* w1     = (const float*)d_in[3];
    const float* b1     = (const float*)d_in[4];
    const float* w2     = (const float*)d_in[5];
    const float* b2     = (const float*)d_in[6];
    const float* atoms  = (const float*)d_in[7];
    const float* router = (const float*)d_in[8];
    const float* cdelta = (const float*)d_in[9];
    const float* rdelta = (const float*)d_in[10];
    const float* chw    = (const float*)d_in[11];
    const float* chb    = (const float*)d_in[12];
    const float* rhw    = (const float*)d_in[13];
    const float* rhb    = (const float*)d_in[14];
    float* out = (float*)d_out;

    // workspace layout (~66 MB)
    double*    xw   = (double*)d_ws;              // [2*1024*512] fp64
    double*    hw   = xw + 1048576;               // [2*1024*512] fp64
    double*    pw   = hw + 1048576;               // [2*1024*512] fp64
    float*     repw = (float*)(pw + 1048576);     // [4*1024*512] fp32
    _Float16*  pf16 = (_Float16*)(repw + 2097152);// [2*1024*512] fp16
    _Float16*  wcw  = pf16 + 1048576;             // [16384*512] fp16
    _Float16*  wrw  = wcw + 8388608;              // [16384*512] fp16

    pool_kernel<<<dim3(1024, 2), 128, 0, stream>>>(ctok, ntok, emb, xw);
    enc_gemm<<<dim3(8, 32), 256, 0, stream>>>(xw, w1, b1, hw, (_Float16*)nullptr, 1);
    enc_gemm<<<dim3(8, 32), 256, 0, stream>>>(hw, w2, b2, pw, pf16, 0);
    combine_kernel<<<8192, 256, 0, stream>>>(router, cdelta, rdelta, wcw, wrw);
    approx_gemm<<<dim3(128, 8, 4), 256, 0, stream>>>(pf16, wcw, wrw, out);
    select_kernel<<<dim3(1024, 4), 256, 0, stream>>>(pw, router, cdelta, rdelta, atoms, out, repw);
    heads_kernel<<<dim3(1024, 2), 256, 0, stream>>>(pw, repw, chw, chb, rhw, rhb, out);
}

// Round 2
// 868.404 us; speedup vs baseline: 1.0646x; 1.0646x over previous
//
#include <hip/hip_runtime.h>

// ---------------------------------------------------------------------------
// SharedAtomModel: pooled-embedding encoder -> sparse dictionary top-k -> heads
//
// Sizes: B=1024 S=32 D=512 DICT=16384 TOPK=32
// Outputs (fp32, flat): [1024x16][1024x6][1024x16][1024x6][4 x 1024x16384]
//
// R2 changes vs R1:
//  - approx_gemm: m97-style async staging (__builtin_amdgcn_global_load_lds,
//    width 16) for A/B tiles — removes VGPR round-trip + address VALU.
//  - select_kernel: approx row held in REGISTERS (8 x uint4 / thread) instead
//    of a 32 KB LDS copy (LDS 45->12 KB, occupancy 3 -> ~5 blocks/CU), and
//    histogram atomics gated to values >= 2*sigma (16384 -> ~750 atomics).
// ---------------------------------------------------------------------------

typedef _Float16 f16x8 __attribute__((ext_vector_type(8)));
typedef _Float16 f16x4 __attribute__((ext_vector_type(4)));
typedef float f32x4 __attribute__((ext_vector_type(4)));

#define OUT_SPARSE 45056
#define SPARSE_PER 16777216

#define ASYNC16(gp, lp) __builtin_amdgcn_global_load_lds(                      \
    (const __attribute__((address_space(1))) void*)(gp),                       \
    (__attribute__((address_space(3))) void*)(lp), 16, 0, 0)

__device__ inline float h2f(unsigned s) {
    _Float16 h = __builtin_bit_cast(_Float16, (unsigned short)(s & 0xFFFFu));
    return (float)h;
}

// ---------------- K1: pooled mean embedding (fp64 accumulate) --------------
__global__ __launch_bounds__(128) void pool_kernel(
    const int* __restrict__ ct, const int* __restrict__ nt,
    const float* __restrict__ emb, double* __restrict__ xout)
{
    const int row = blockIdx.x, s = blockIdx.y;
    const int tid = threadIdx.x;
    __shared__ int tk[32];
    const int* t = (s ? nt : ct) + row * 32;
    if (tid < 32) tk[tid] = t[tid];
    __syncthreads();
    const int d = tid * 4;
    double a0 = 0, a1 = 0, a2 = 0, a3 = 0;
    for (int i = 0; i < 32; ++i) {
        const float4 v = *(const float4*)(emb + (size_t)tk[i] * 512 + d);
        a0 += (double)v.x; a1 += (double)v.y; a2 += (double)v.z; a3 += (double)v.w;
    }
    double* o = xout + ((size_t)s * 1024 + row) * 512 + d;
    o[0] = a0 * 0.03125; o[1] = a1 * 0.03125; o[2] = a2 * 0.03125; o[3] = a3 * 0.03125;
}

// ---------------- K2/K3: fp64 encoder GEMM: C = f(A @ W^T + b) -------------
__global__ __launch_bounds__(256) void enc_gemm(
    const double* __restrict__ A, const float* __restrict__ W,
    const float* __restrict__ bias, double* __restrict__ C,
    _Float16* __restrict__ C16, int act)
{
    __shared__ double Ask[16][68];
    __shared__ double Wsk[16][68];
    const int tid = threadIdx.x;
    const int m0 = blockIdx.y * 64, n0 = blockIdx.x * 64;
    const int ty = tid >> 4, tx = tid & 15;
    const int r = tid >> 2, c4 = (tid & 3) * 4;
    double acc[4][4] = {};
    for (int k0 = 0; k0 < 512; k0 += 16) {
        const double4 av = *(const double4*)(A + (size_t)(m0 + r) * 512 + k0 + c4);
        const float4  wv = *(const float4*) (W + (size_t)(n0 + r) * 512 + k0 + c4);
        __syncthreads();
        Ask[c4 + 0][r] = av.x; Ask[c4 + 1][r] = av.y; Ask[c4 + 2][r] = av.z; Ask[c4 + 3][r] = av.w;
        Wsk[c4 + 0][r] = (double)wv.x; Wsk[c4 + 1][r] = (double)wv.y;
        Wsk[c4 + 2][r] = (double)wv.z; Wsk[c4 + 3][r] = (double)wv.w;
        __syncthreads();
#pragma unroll
        for (int k = 0; k < 16; ++k) {
            const double4 a = *(const double4*)&Ask[k][ty * 4];
            const double4 b = *(const double4*)&Wsk[k][tx * 4];
            const double aa[4] = {a.x, a.y, a.z, a.w};
            const double bb[4] = {b.x, b.y, b.z, b.w};
#pragma unroll
            for (int i = 0; i < 4; ++i)
#pragma unroll
                for (int j = 0; j < 4; ++j) acc[i][j] += aa[i] * bb[j];
        }
    }
#pragma unroll
    for (int i = 0; i < 4; ++i) {
        const int row = m0 + ty * 4 + i;
#pragma unroll
        for (int j = 0; j < 4; ++j) {
            const int col = n0 + tx * 4 + j;
            double v = acc[i][j] + (double)bias[col];
            if (act) v = v / (1.0 + exp(-v));   // silu
            C[(size_t)row * 512 + col] = v;
            if (C16) C16[(size_t)row * 512 + col] = (_Float16)v;
        }
    }
}

// ---------------- K4: combined fp16 weights --------------------------------
__global__ __launch_bounds__(256) void combine_kernel(
    const float* __restrict__ router, const float* __restrict__ cd,
    const float* __restrict__ rd, _Float16* __restrict__ wc,
    _Float16* __restrict__ wr)
{
    const size_t i = ((size_t)blockIdx.x * 256 + threadIdx.x) * 4;
    if (i >= (size_t)16384 * 512) return;
    const float4 r = *(const float4*)(router + i);
    const float4 c = *(const float4*)(cd + i);
    const float4 d = *(const float4*)(rd + i);
    f16x4 hc = { (_Float16)(r.x + 0.3f * c.x), (_Float16)(r.y + 0.3f * c.y),
                 (_Float16)(r.z + 0.3f * c.z), (_Float16)(r.w + 0.3f * c.w) };
    f16x4 hr = { (_Float16)(r.x + 0.3f * d.x), (_Float16)(r.y + 0.3f * d.y),
                 (_Float16)(r.z + 0.3f * d.z), (_Float16)(r.w + 0.3f * d.w) };
    *(f16x4*)(wc + i) = hc;
    *(f16x4*)(wr + i) = hr;
}

// ---------------- K5: fp16 MFMA approx coeff GEMM (m97-style staging) ------
// C[1024 x 16384] (per combo) = P[1024x512] @ W[16384x512]^T, fp16 out staged
// into the first half of each output row of the sparse region.
__global__ __launch_bounds__(256) void approx_gemm(
    const _Float16* __restrict__ P, const _Float16* __restrict__ Wc,
    const _Float16* __restrict__ Wr, float* __restrict__ outf)
{
    __shared__ _Float16 As[128 * 32];
    __shared__ _Float16 Bs[128 * 32];
    __shared__ _Float16 Cst[128 * 128];

    const int tid = threadIdx.x;
    const int q = blockIdx.z;
    const int n0 = blockIdx.x * 128, m0 = blockIdx.y * 128;
    const _Float16* A = P + (size_t)(q >> 1) * 524288;
    const _Float16* B = (q & 1) ? Wr : Wc;

    const int lane = tid & 63, w = tid >> 6;
    const int wm = w & 1, wn = w >> 1;
    const int lr = lane & 15, lk = lane >> 4;

    // async-staging addressing: wave w stages chunks {2w, 2w+1} of each 8 KB
    // tile; lane covers 16 B at row chunk*16 + lane/4, halves (lane&3)*8.
    const int ch0 = w * 2, ch1 = w * 2 + 1;
    const int lrow = lane >> 2, lh = (lane & 3) * 8;
    const _Float16* Ag0 = A + (size_t)(m0 + ch0 * 16 + lrow) * 512 + lh;
    const _Float16* Ag1 = A + (size_t)(m0 + ch1 * 16 + lrow) * 512 + lh;
    const _Float16* Bg0 = B + (size_t)(n0 + ch0 * 16 + lrow) * 512 + lh;
    const _Float16* Bg1 = B + (size_t)(n0 + ch1 * 16 + lrow) * 512 + lh;
    _Float16* Al0 = As + ch0 * 512;   // wave-uniform LDS bases (chunk*1024 B)
    _Float16* Al1 = As + ch1 * 512;
    _Float16* Bl0 = Bs + ch0 * 512;
    _Float16* Bl1 = Bs + ch1 * 512;

    const f32x4 zero = {0.f, 0.f, 0.f, 0.f};
    f32x4 acc[4][4];
#pragma unroll
    for (int i = 0; i < 4; ++i)
#pragma unroll
        for (int j = 0; j < 4; ++j) acc[i][j] = zero;

    for (int kt = 0; kt < 16; ++kt) {
        const int k0 = kt * 32;
        __syncthreads();                 // prev iter's ds_reads done
        ASYNC16(Ag0 + k0, Al0);
        ASYNC16(Ag1 + k0, Al1);
        ASYNC16(Bg0 + k0, Bl0);
        ASYNC16(Bg1 + k0, Bl1);
        __syncthreads();                 // implies vmcnt(0): LDS tiles ready
        f16x8 af[4], bf[4];
#pragma unroll
        for (int i = 0; i < 4; ++i) af[i] = *(const f16x8*)(As + (wm * 64 + i * 16 + lr) * 32 + lk * 8);
#pragma unroll
        for (int j = 0; j < 4; ++j) bf[j] = *(const f16x8*)(Bs + (wn * 64 + j * 16 + lr) * 32 + lk * 8);
#pragma unroll
        for (int i = 0; i < 4; ++i)
#pragma unroll
            for (int j = 0; j < 4; ++j)
                acc[i][j] = __builtin_amdgcn_mfma_f32_16x16x32_f16(af[i], bf[j], acc[i][j], 0, 0, 0);
    }
    __syncthreads();
    // C/D layout: col = lane&15, row = (lane>>4)*4 + reg  [m89-verified]
#pragma unroll
    for (int i = 0; i < 4; ++i)
#pragma unroll
        for (int j = 0; j < 4; ++j)
#pragma unroll
            for (int rr = 0; rr < 4; ++rr)
                Cst[(wm * 64 + i * 16 + lk * 4 + rr) * 128 + (wn * 64 + j * 16 + lr)] =
                    (_Float16)acc[i][j][rr];
    __syncthreads();
    // coalesced 16B stores; row stride in the sparse region = 32768 ushorts
    unsigned short* ob = (unsigned short*)outf + (size_t)2 * OUT_SPARSE + (size_t)q * 2 * SPARSE_PER;
#pragma unroll
    for (int p = 0; p < 8; ++p) {
        const int cc = p * 256 + tid;
        const int rl = cc >> 4;
        const int chh = (cc & 15) * 8;
        const float4 v = *(const float4*)(Cst + rl * 128 + chh);
        *(float4*)(ob + (size_t)(m0 + rl) * 32768 + n0 + chh) = v;
    }
}

// ---------------- K6: select + exact recompute + scatter + rep -------------
__global__ __launch_bounds__(256) void select_kernel(
    const double* __restrict__ pw, const float* __restrict__ router,
    const float* __restrict__ cdelta, const float* __restrict__ rdelta,
    const float* __restrict__ atoms, float* __restrict__ outf,
    float* __restrict__ repw)
{
    constexpr int NCAP = 160, NRE = 64;
    const int row = blockIdx.x, q = blockIdx.y;
    const int pset = q >> 1;
    const int tid = threadIdx.x;

    __shared__ unsigned hist[1024];
    __shared__ unsigned pscan[256];
    __shared__ double prow[512];
    __shared__ int cidx[NCAP];
    __shared__ unsigned short ckey[NCAP];
    __shared__ int r64i[NRE];
    __shared__ double cval[NRE];
    __shared__ float selv[32];
    __shared__ int seli[32];
    __shared__ float wred[4];
    __shared__ int cnt, bstar;
    __shared__ unsigned cutk_s;

    float* orow = outf + (size_t)OUT_SPARSE + (size_t)q * SPARSE_PER + (size_t)row * 16384;
    const double* prg = pw + ((size_t)pset * 1024 + row) * 512;

    for (int b = tid; b < 1024; b += 256) hist[b] = 0;
    if (tid == 0) { cnt = 0; bstar = -1; }
    prow[tid] = prg[tid];
    prow[tid + 256] = prg[tid + 256];

    // approx fp16 row -> registers (32 dwords/thread)
    uint4 rv[8];
    const uint4* ar4 = (const uint4*)orow;
#pragma unroll
    for (int p = 0; p < 8; ++p) rv[p] = ar4[p * 256 + tid];

    // per-row sigma from sum of squares (registers, no atomics)
    float ss = 0.f;
#pragma unroll
    for (int p = 0; p < 8; ++p) {
        const unsigned uu[4] = {rv[p].x, rv[p].y, rv[p].z, rv[p].w};
#pragma unroll
        for (int e = 0; e < 4; ++e) {
            const float f0 = h2f(uu[e]), f1 = h2f(uu[e] >> 16);
            ss = fmaf(f0, f0, ss);
            ss = fmaf(f1, f1, ss);
        }
    }
    for (int sh = 32; sh > 0; sh >>= 1) ss += __shfl_down(ss, sh);
    const int w = tid >> 6, lane = tid & 63;
    if (lane == 0) wred[w] = ss;
    __syncthreads();
    if (tid == 0) {
        const float sig = sqrtf((wred[0] + wred[1] + wred[2] + wred[3]) * (1.f / 16384.f));
        const _Float16 h = (_Float16)(2.0f * sig);
        cutk_s = (unsigned)__builtin_bit_cast(unsigned short, h) & 0x7FFFu;
    }
    __syncthreads();
    const unsigned cutk = cutk_s;

    // sparse histogram: only values >= 2*sigma (expected ~750 of 16384)
#pragma unroll
    for (int p = 0; p < 8; ++p) {
        const unsigned uu[4] = {rv[p].x, rv[p].y, rv[p].z, rv[p].w};
#pragma unroll
        for (int e = 0; e < 4; ++e) {
            const unsigned k0 = uu[e] & 0x7FFFu, k1 = (uu[e] >> 16) & 0x7FFFu;
            if (k0 >= cutk) atomicAdd(&hist[k0 >> 5], 1u);
            if (k1 >= cutk) atomicAdd(&hist[k1 >> 5], 1u);
        }
    }
    __syncthreads();

    // zero-fill the dense output row (approx copy lives in registers)
    const float4 z4 = {0.f, 0.f, 0.f, 0.f};
    float4* o4 = (float4*)orow;
#pragma unroll
    for (int p = 0; p < 16; ++p) o4[p * 256 + tid] = z4;

    // suffix-scan histogram from the top to find candidate key threshold
    const unsigned h0 = hist[tid * 4], h1 = hist[tid * 4 + 1];
    const unsigned h2 = hist[tid * 4 + 2], h3 = hist[tid * 4 + 3];
    const unsigned l3 = h3, l2 = h2 + l3, l1 = h1 + l2, l0 = h0 + l1;
    pscan[tid] = l0;
    __syncthreads();
    for (int s = 1; s < 256; s <<= 1) {
        const unsigned v = (tid + s < 256) ? pscan[tid + s] : 0u;
        __syncthreads();
        pscan[tid] += v;
        __syncthreads();
    }
    {
        const unsigned above = (tid < 255) ? pscan[tid + 1] : 0u;
        int best = -1;
        if (l0 + above >= 64u) best = tid * 4;
        if (l1 + above >= 64u) best = tid * 4 + 1;
        if (l2 + above >= 64u) best = tid * 4 + 2;
        if (l3 + above >= 64u) best = tid * 4 + 3;
        if (best >= 0) atomicMax(&bstar, best);
    }
    __syncthreads();
    const unsigned kmin = (unsigned)(bstar < 0 ? 0 : bstar) << 5;

    // collect candidates from registers (superset of approx top-64)
#pragma unroll
    for (int p = 0; p < 8; ++p) {
        const unsigned uu[4] = {rv[p].x, rv[p].y, rv[p].z, rv[p].w};
        const int base = (p * 256 + tid) * 8;
#pragma unroll
        for (int e = 0; e < 4; ++e) {
            const unsigned k0 = uu[e] & 0x7FFFu, k1 = (uu[e] >> 16) & 0x7FFFu;
            if (k0 >= kmin) { const int pos = atomicAdd(&cnt, 1); if (pos < NCAP) { cidx[pos] = base + e * 2;     ckey[pos] = (unsigned short)k0; } }
            if (k1 >= kmin) { const int pos = atomicAdd(&cnt, 1); if (pos < NCAP) { cidx[pos] = base + e * 2 + 1; ckey[pos] = (unsigned short)k1; } }
        }
    }
    __syncthreads();
    const int nc = min(cnt, NCAP);

    // approx-rank candidates; keep top NRE (rank unique => race-free)
    for (int p = tid; p < nc; p += 256) {
        const unsigned mk = ckey[p];
        const int mi = cidx[p];
        int rr = 0;
        for (int j = 0; j < nc; ++j) {
            const unsigned kj = ckey[j];
            rr += (kj > mk || (kj == mk && cidx[j] < mi)) ? 1 : 0;
        }
        if (rr < NRE) r64i[rr] = mi;
    }
    __syncthreads();

    // exact fp64 recompute: c = p.router_row + 0.3 * p.delta_row
    const float* drow = (q & 1) ? rdelta : cdelta;
    for (int c = w; c < NRE; c += 4) {
        const int idx = r64i[c];
        const float4* rp4 = (const float4*)(router + (size_t)idx * 512);
        const float4* dp4 = (const float4*)(drow + (size_t)idx * 512);
        const float4 r0 = rp4[lane * 2], r1 = rp4[lane * 2 + 1];
        const float4 d0 = dp4[lane * 2], d1 = dp4[lane * 2 + 1];
        const double* pv = prow + lane * 8;
        double aR = pv[0] * (double)r0.x + pv[1] * (double)r0.y + pv[2] * (double)r0.z + pv[3] * (double)r0.w
                  + pv[4] * (double)r1.x + pv[5] * (double)r1.y + pv[6] * (double)r1.z + pv[7] * (double)r1.w;
        double aD = pv[0] * (double)d0.x + pv[1] * (double)d0.y + pv[2] * (double)d0.z + pv[3] * (double)d0.w
                  + pv[4] * (double)d1.x + pv[5] * (double)d1.y + pv[6] * (double)d1.z + pv[7] * (double)d1.w;
        for (int sh = 32; sh > 0; sh >>= 1) { aR += __shfl_down(aR, sh); aD += __shfl_down(aD, sh); }
        if (lane == 0) cval[c] = aR + 0.3 * aD;
    }
    __syncthreads();

    // exact top-32 by (|v| desc, idx asc) -- matches lax.top_k tie semantics
    if (tid < NRE) {
        const double av = fabs(cval[tid]);
        const int mi = r64i[tid];
        int rr = 0;
        for (int j = 0; j < NRE; ++j) {
            const double aj = fabs(cval[j]);
            rr += (aj > av || (aj == av && r64i[j] < mi)) ? 1 : 0;
        }
        if (rr < 32) {
            const float fv = (float)cval[tid];
            selv[rr] = fv; seli[rr] = mi;
            orow[mi] = fv;                       // scatter signed value
        }
    }
    __syncthreads();

    // rep = sum_k v_k * atoms[idx_k]
    double a0 = 0, a1 = 0;
    for (int k = 0; k < 32; ++k) {
        const double v = (double)selv[k];
        const float* ar = atoms + (size_t)seli[k] * 512;
        a0 += v * (double)ar[tid];
        a1 += v * (double)ar[tid + 256];
    }
    float* rp = repw + ((size_t)q * 1024 + row) * 512;
    rp[tid] = (float)a0;
    rp[tid + 256] = (float)a1;
}

// ---------------- K7: fused + heads ----------------------------------------
__global__ __launch_bounds__(256) void heads_kernel(
    const double* __restrict__ pw, const float* __restrict__ repw,
    const float* __restrict__ chw, const float* __restrict__ chb,
    const float* __restrict__ rhw, const float* __restrict__ rhb,
    float* __restrict__ out)
{
    const int row = blockIdx.x, s = blockIdx.y;
    const int tid = threadIdx.x;
    __shared__ double fused[512];
    const double* pr = pw + ((size_t)s * 1024 + row) * 512;
    const float* rc = repw + ((size_t)(s * 2 + 0) * 1024 + row) * 512;
    const float* rr = repw + ((size_t)(s * 2 + 1) * 1024 + row) * 512;
    for (int d = tid; d < 512; d += 256)
        fused[d] = 0.2 * pr[d] + 0.9 * (double)rc[d] + 0.9 * (double)rr[d];
    __syncthreads();
    const int w = tid >> 6, lane = tid & 63;
    for (int o = w; o < 22; o += 4) {
        const float* hw = (o < 16) ? (chw + (size_t)o * 512) : (rhw + (size_t)(o - 16) * 512);
        double acc = 0;
#pragma unroll
        for (int j = 0; j < 8; ++j) acc += fused[lane + 64 * j] * (double)hw[lane + 64 * j];
        for (int sh = 32; sh > 0; sh >>= 1) acc += __shfl_down(acc, sh);
        if (lane == 0) {
            if (o < 16) out[(s ? 22528 : 0) + row * 16 + o] = (float)(acc + (double)chb[o]);
            else        out[(s ? 38912 : 16384) + row * 6 + (o - 16)] = (float)(acc + (double)rhb[o - 16]);
        }
    }
}

// ---------------------------------------------------------------------------
extern "C" void kernel_launch(void* const* d_in, const int* in_sizes, int n_in,
                              void* d_out, int out_size, void* d_ws, size_t ws_size,
                              hipStream_t stream)
{
    const int*   ctok   = (const int*)d_in[0];
    const int*   ntok   = (const int*)d_in[1];
    const float* emb    = (const float*)d_in[2];
    const float* w1     = (const float*)d_in[3];
    const float* b1     = (const float*)d_in[4];
    const float* w2     = (const float*)d_in[5];
    const float* b2     = (const float*)d_in[6];
    const float* atoms  = (const float*)d_in[7];
    const float* router = (const float*)d_in[8];
    const float* cdelta = (const float*)d_in[9];
    const float* rdelta = (const float*)d_in[10];
    const float* chw    = (const float*)d_in[11];
    const float* chb    = (const float*)d_in[12];
    const float* rhw    = (const float*)d_in[13];
    const float* rhb    = (const float*)d_in[14];
    float* out = (float*)d_out;

    // workspace layout (~66 MB)
    double*    xw   = (double*)d_ws;              // [2*1024*512] fp64
    double*    hw   = xw + 1048576;               // [2*1024*512] fp64
    double*    pw   = hw + 1048576;               // [2*1024*512] fp64
    float*     repw = (float*)(pw + 1048576);     // [4*1024*512] fp32
    _Float16*  pf16 = (_Float16*)(repw + 2097152);// [2*1024*512] fp16
    _Float16*  wcw  = pf16 + 1048576;             // [16384*512] fp16
    _Float16*  wrw  = wcw + 8388608;              // [16384*512] fp16

    pool_kernel<<<dim3(1024, 2), 128, 0, stream>>>(ctok, ntok, emb, xw);
    enc_gemm<<<dim3(8, 32), 256, 0, stream>>>(xw, w1, b1, hw, (_Float16*)nullptr, 1);
    enc_gemm<<<dim3(8, 32), 256, 0, stream>>>(hw, w2, b2, pw, pf16, 0);
    combine_kernel<<<8192, 256, 0, stream>>>(router, cdelta, rdelta, wcw, wrw);
    approx_gemm<<<dim3(128, 8, 4), 256, 0, stream>>>(pf16, wcw, wrw, out);
    select_kernel<<<dim3(1024, 4), 256, 0, stream>>>(pw, router, cdelta, rdelta, atoms, out, repw);
    heads_kernel<<<dim3(1024, 2), 256, 0, stream>>>(pw, repw, chw, chb, rhw, rhb, out);
}